// Round 7
// baseline (266.123 us; speedup 1.0000x reference)
//
#include <hip/hip_runtime.h>
#include <math.h>

#define BATCH 4
#define NPTS 4096
#define DF 64
#define ROWB 128               // bytes per point row in bf16
#define TILE 64                // col tile per iter
#define MC 4                   // col splits for occupancy
#define CHUNK (NPTS / MC)      // 1024
#define ITERS (CHUNK / TILE)   // 16
#define INV_T 100.0f
#define MARGIN 0.16f           // skipped weights < exp(-16) ~ 1.1e-7
#define SCALE (1.0f / 16384.0f)

typedef float  f32x4 __attribute__((ext_vector_type(4)));
typedef short  s16x8 __attribute__((ext_vector_type(8)));
typedef unsigned short u16;

// ws layout (6.19 MB, proven in R2/R4)
#define SZ_B   (BATCH * NPTS * DF * 2)   // bf16 array: 2 MB
#define SZ_N   (BATCH * NPTS * 4)        // norm array: 64 KB
#define OFF_XB 0
#define OFF_YB (OFF_XB + SZ_B)
#define OFF_X2 (OFF_YB + SZ_B)
#define OFF_Y2 (OFF_X2 + SZ_N)
#define OFF_PART (OFF_Y2 + SZ_N)         // [dir*4+b][MC][NPTS][4] floats: 2 MB

__device__ __forceinline__ u16 f2bf(float f) {
    unsigned u = __float_as_uint(f);
    unsigned r = (u + 0x7fffu + ((u >> 16) & 1u)) >> 16;   // RNE
    return (u16)r;
}

// async 16B global -> LDS (DMA, no VGPR round-trip)
__device__ __forceinline__ void async16(void* lds, const void* g) {
    __builtin_amdgcn_global_load_lds(
        (const __attribute__((address_space(1))) unsigned int*)g,
        (__attribute__((address_space(3))) unsigned int*)lds, 16, 0, 0);
}

// fp32 -> bf16 (XOR-swizzled row layout: byte ^= (point&7)<<4) + fp32 norms.
// Pre-swizzling in global: linear global_load_lds DMA reproduces the
// bank-conflict-free LDS layout, and register fragment loads can read the
// same offsets directly from global (m173 pattern).
__global__ __launch_bounds__(256) void prep_kernel(const float* __restrict__ X,
                                                   const float* __restrict__ Y,
                                                   u16* __restrict__ xb, u16* __restrict__ yb,
                                                   float* __restrict__ x2, float* __restrict__ y2) {
    const float* src = blockIdx.y ? Y : X;
    u16* dstb   = blockIdx.y ? yb : xb;
    float* dstn = blockIdx.y ? y2 : x2;
    int g = blockIdx.x * 256 + threadIdx.x;
    int p = g >> 4;                       // point 0..16383
    int sub = g & 15;                     // 8B chunk within row
    float4 v = ((const float4*)src)[(size_t)p * 16 + sub];
    float n4 = v.x * v.x + v.y * v.y + v.z * v.z + v.w * v.w;
    #pragma unroll
    for (int m = 1; m < 16; m <<= 1) n4 += __shfl_xor(n4, m, 16);
    ushort4 hh;
    hh.x = f2bf(v.x); hh.y = f2bf(v.y); hh.z = f2bf(v.z); hh.w = f2bf(v.w);
    int byteoff = (sub << 3) ^ ((p & 7) << 4);   // swizzle (XOR bits 4..6)
    *(ushort4*)((char*)dstb + (size_t)p * ROWB + byteoff) = hh;
    if (sub == 0) dstn[p] = n4;
}

// Two-phase partial softmin. Block = 64 rows x 1024 cols of one (b, dir).
// Wave tiling 2x2. Pass 1: exact chunk max of u = xy - y2/2 (-> exact min d).
// Pass 2: per-(st,ct,r) gated weighted sums. No x-LDS: A-frags direct from
// pre-swizzled global. LDS 17.2 KB -> 8 blocks/CU (thread-cap limited).
__global__ __launch_bounds__(256, 8) void softmin_fused(const u16* __restrict__ xb,
                                                        const u16* __restrict__ yb,
                                                        const float* __restrict__ x2g,
                                                        const float* __restrict__ y2g,
                                                        float* __restrict__ part) {
    __shared__ u16 ys[2][TILE * DF];     // 2 x 8 KB double buffer
    __shared__ float xchg[4][32][2];

    const int tid = threadIdx.x;
    const int nt  = blockIdx.x;
    const int b   = blockIdx.y & 3;
    const int cs  = blockIdx.y >> 2;
    const int dir = blockIdx.z;

    const u16 *rowsrc, *colsrc; const float *rn, *cn;
    if (dir == 0) { rowsrc = xb; colsrc = yb; rn = x2g; cn = y2g; }
    else          { rowsrc = yb; colsrc = xb; rn = y2g; cn = x2g; }

    const int w    = tid >> 6;
    const int wrow = w >> 1, wcol = w & 1;
    const int h    = (tid >> 4) & 3;     // k-octet / D-row group
    const int c    = tid & 15;           // fragment lane slot

    const size_t bpts = (size_t)b * NPTS;
    const int row0 = nt * TILE;
    const u16* rbase = rowsrc + (bpts + row0) * DF;
    const u16* cbase = colsrc + (bpts + (size_t)cs * CHUNK) * DF;
    const float* cnb = cn + bpts + (size_t)cs * CHUNK;

    // loop-invariant B fragment offsets + col point ids
    int boff[2][2], pty[2];
    #pragma unroll
    for (int ct = 0; ct < 2; ++ct) {
        int p = (wcol * 2 + ct) * 16 + c;
        pty[ct] = p;
        #pragma unroll
        for (int kp = 0; kp < 2; ++kp)
            boff[ct][kp] = p * ROWB + ((h * 16 + kp * 64) ^ ((p & 7) << 4));
    }

    // ---- prologue: DMA first y tile; A-frags + norms direct from global ----
    #pragma unroll
    for (int q = 0; q < 2; ++q) {
        int e = q * 256 + tid;
        async16((char*)ys[0] + e * 16, (const char*)cbase + e * 16);
    }
    float cy[2] = { cnb[pty[0]], cnb[pty[1]] };

    // A fragments (persistent in registers) from pre-swizzled global
    s16x8 afrag[2][2];
    #pragma unroll
    for (int st = 0; st < 2; ++st) {
        int rr = (wrow * 2 + st) * 16 + c;
        #pragma unroll
        for (int kp = 0; kp < 2; ++kp) {
            int o = (h * 16 + kp * 64) ^ ((rr & 7) << 4);
            afrag[st][kp] = *(const s16x8*)((const char*)rbase + rr * ROWB + o);
        }
    }
    float x2v[2][4];
    #pragma unroll
    for (int st = 0; st < 2; ++st)
        #pragma unroll
        for (int r = 0; r < 4; ++r)
            x2v[st][r] = rn[bpts + row0 + (wrow * 2 + st) * 16 + 4 * h + r];

    float mx[2][4];
    #pragma unroll
    for (int st = 0; st < 2; ++st)
        #pragma unroll
        for (int r = 0; r < 4; ++r) mx[st][r] = -INFINITY;

    __syncthreads();   // drains vmcnt(0): ys[0] ready

    // ================= PASS 1: exact chunk max of u = acc - y2/2 =================
    for (int it = 0; it < ITERS; ++it) {
        if (it > 0) __syncthreads();     // waits this iter's DMA (vmcnt 0) + barrier
        float ccy[2] = { cy[0], cy[1] };
        if (it + 1 < ITERS) {            // issue next tile AFTER barrier (overlaps compute)
            const char* nsrc = (const char*)(cbase + (size_t)(it + 1) * TILE * DF);
            char* nbuf = (char*)ys[(it + 1) & 1];
            #pragma unroll
            for (int q = 0; q < 2; ++q) {
                int e = q * 256 + tid;
                async16(nbuf + e * 16, nsrc + e * 16);
            }
            cy[0] = cnb[(it + 1) * TILE + pty[0]];
            cy[1] = cnb[(it + 1) * TILE + pty[1]];
        }
        const char* bptr = (const char*)ys[it & 1];

        s16x8 bf[2][2];
        #pragma unroll
        for (int ct = 0; ct < 2; ++ct)
            #pragma unroll
            for (int kp = 0; kp < 2; ++kp)
                bf[ct][kp] = *(const s16x8*)(bptr + boff[ct][kp]);
        #pragma unroll
        for (int st = 0; st < 2; ++st)
            #pragma unroll
            for (int ct = 0; ct < 2; ++ct) {
                f32x4 a = {0.f, 0.f, 0.f, 0.f};
                a = __builtin_amdgcn_mfma_f32_16x16x32_bf16(afrag[st][0], bf[ct][0], a, 0, 0, 0);
                a = __builtin_amdgcn_mfma_f32_16x16x32_bf16(afrag[st][1], bf[ct][1], a, 0, 0, 0);
                // pairwise to invite v_max3 fusion
                float u0 = fmaf(-0.5f, ccy[ct], a[0]);
                float u1 = fmaf(-0.5f, ccy[ct], a[1]);
                float u2 = fmaf(-0.5f, ccy[ct], a[2]);
                float u3 = fmaf(-0.5f, ccy[ct], a[3]);
                mx[st][0] = fmaxf(mx[st][0], u0);
                mx[st][1] = fmaxf(mx[st][1], u1);
                mx[st][2] = fmaxf(mx[st][2], u2);
                mx[st][3] = fmaxf(mx[st][3], u3);
            }
    }

    // butterfly max within 16-lane col groups, then share across wcol pair
    #pragma unroll
    for (int st = 0; st < 2; ++st)
        #pragma unroll
        for (int r = 0; r < 4; ++r)
            #pragma unroll
            for (int m = 1; m < 16; m <<= 1)
                mx[st][r] = fmaxf(mx[st][r], __shfl_xor(mx[st][r], m, 16));
    __syncthreads();
    if (c == 0) {
        #pragma unroll
        for (int st = 0; st < 2; ++st)
            #pragma unroll
            for (int r = 0; r < 4; ++r)
                xchg[w][st * 16 + 4 * h + r][0] = mx[st][r];
    }
    __syncthreads();
    #pragma unroll
    for (int st = 0; st < 2; ++st)
        #pragma unroll
        for (int r = 0; r < 4; ++r)
            mx[st][r] = fmaxf(mx[st][r], xchg[w ^ 1][st * 16 + 4 * h + r][0]);

    float mval[2][4], gthr[2][4], ssum[2][4], tsum[2][4];
    #pragma unroll
    for (int st = 0; st < 2; ++st)
        #pragma unroll
        for (int r = 0; r < 4; ++r) {
            float d2m = fmaf(-2.f, mx[st][r], x2v[st][r]);   // exact min d^2
            mval[st][r] = sqrtf(fmaxf(d2m, 0.f));
            gthr[st][r] = mx[st][r] - MARGIN * mval[st][r] - 0.5f * MARGIN * MARGIN;
            ssum[st][r] = 0.f; tsum[st][r] = 0.f;
        }

    // re-prologue for pass 2 (safe: pass-1 reads fully done)
    #pragma unroll
    for (int q = 0; q < 2; ++q) {
        int e = q * 256 + tid;
        async16((char*)ys[0] + e * 16, (const char*)cbase + e * 16);
    }
    cy[0] = cnb[pty[0]]; cy[1] = cnb[pty[1]];

    // ================= PASS 2: gated weighted sums =================
    for (int it = 0; it < ITERS; ++it) {
        __syncthreads();                 // waits this iter's DMA + barrier
        float ccy[2] = { cy[0], cy[1] };
        if (it + 1 < ITERS) {
            const char* nsrc = (const char*)(cbase + (size_t)(it + 1) * TILE * DF);
            char* nbuf = (char*)ys[(it + 1) & 1];
            #pragma unroll
            for (int q = 0; q < 2; ++q) {
                int e = q * 256 + tid;
                async16(nbuf + e * 16, nsrc + e * 16);
            }
            cy[0] = cnb[(it + 1) * TILE + pty[0]];
            cy[1] = cnb[(it + 1) * TILE + pty[1]];
        }
        const char* bptr = (const char*)ys[it & 1];

        s16x8 bf[2][2];
        #pragma unroll
        for (int ct = 0; ct < 2; ++ct)
            #pragma unroll
            for (int kp = 0; kp < 2; ++kp)
                bf[ct][kp] = *(const s16x8*)(bptr + boff[ct][kp]);
        #pragma unroll
        for (int st = 0; st < 2; ++st)
            #pragma unroll
            for (int ct = 0; ct < 2; ++ct) {
                f32x4 a = {0.f, 0.f, 0.f, 0.f};
                a = __builtin_amdgcn_mfma_f32_16x16x32_bf16(afrag[st][0], bf[ct][0], a, 0, 0, 0);
                a = __builtin_amdgcn_mfma_f32_16x16x32_bf16(afrag[st][1], bf[ct][1], a, 0, 0, 0);
                #pragma unroll
                for (int r = 0; r < 4; ++r) {
                    float u = fmaf(-0.5f, ccy[ct], a[r]);
                    if (__any(u > gthr[st][r])) {    // 4-row x 16-col slice, ~9% fire
                        float d2 = fmaf(-2.f, u, x2v[st][r]);
                        float d = sqrtf(fmaxf(d2, 0.f));
                        float e = __expf(INV_T * (mval[st][r] - d));  // ->0 if far
                        ssum[st][r] += e;
                        tsum[st][r] = fmaf(e, d, tsum[st][r]);
                    }
                }
            }
    }

    // butterfly sums within 16-lane col groups
    #pragma unroll
    for (int st = 0; st < 2; ++st)
        #pragma unroll
        for (int r = 0; r < 4; ++r)
            #pragma unroll
            for (int m = 1; m < 16; m <<= 1) {
                ssum[st][r] += __shfl_xor(ssum[st][r], m, 16);
                tsum[st][r] += __shfl_xor(tsum[st][r], m, 16);
            }

    // cross-wcol add and partial-state write
    __syncthreads();
    if (c == 0) {
        #pragma unroll
        for (int st = 0; st < 2; ++st)
            #pragma unroll
            for (int r = 0; r < 4; ++r) {
                xchg[w][st * 16 + 4 * h + r][0] = ssum[st][r];
                xchg[w][st * 16 + 4 * h + r][1] = tsum[st][r];
            }
    }
    __syncthreads();
    if (wcol == 0 && c == 0) {
        int dirb = dir * 4 + b;
        #pragma unroll
        for (int st = 0; st < 2; ++st)
            #pragma unroll
            for (int r = 0; r < 4; ++r) {
                int row32 = st * 16 + 4 * h + r;
                float S = ssum[st][r] + xchg[w + 1][row32][0];
                float T = tsum[st][r] + xchg[w + 1][row32][1];
                int row = row0 + wrow * 32 + row32;
                float* pp = part + (((size_t)(dirb * MC + cs)) * NPTS + row) * 4;
                pp[0] = mval[st][r]; pp[1] = S; pp[2] = T;
            }
    }
}

// Merge MC partial states per row, cube, reduce, atomicAdd into out[0].
__global__ __launch_bounds__(256) void merge_kernel(const float* __restrict__ part,
                                                    float* __restrict__ out) {
    __shared__ float red[4];
    int g = blockIdx.x * 256 + threadIdx.x;   // (dir*4+b)*4096 + row
    int dirb = g >> 12;
    int row  = g & 4095;
    const float* p0 = part + (((size_t)dirb * MC) * NPTS + row) * 4;
    float mnv[MC], sv[MC], tv[MC];
    float nm = INFINITY;
    #pragma unroll
    for (int k = 0; k < MC; ++k) {
        const float* p = p0 + (size_t)k * NPTS * 4;
        mnv[k] = p[0]; sv[k] = p[1]; tv[k] = p[2];
        nm = fminf(nm, mnv[k]);
    }
    float S = 0.f, T = 0.f;
    #pragma unroll
    for (int k = 0; k < MC; ++k) {
        float cw = __expf(INV_T * (nm - mnv[k]));
        S += sv[k] * cw;
        T += tv[k] * cw;
    }
    float sm = T / S;
    float v = sm * sm * sm * SCALE;
    #pragma unroll
    for (int m = 1; m < 64; m <<= 1) v += __shfl_xor(v, m, 64);
    if ((threadIdx.x & 63) == 0) red[threadIdx.x >> 6] = v;
    __syncthreads();
    if (threadIdx.x == 0) atomicAdd(out, red[0] + red[1] + red[2] + red[3]);
}

__global__ void zero_kernel(float* out) {
    if (threadIdx.x == 0) out[0] = 0.0f;
}

extern "C" void kernel_launch(void* const* d_in, const int* in_sizes, int n_in,
                              void* d_out, int out_size, void* d_ws, size_t ws_size,
                              hipStream_t stream) {
    const float* x = (const float*)d_in[0];
    const float* y = (const float*)d_in[1];
    float* out = (float*)d_out;
    char* ws = (char*)d_ws;

    u16* xb = (u16*)(ws + OFF_XB);
    u16* yb = (u16*)(ws + OFF_YB);
    float* x2 = (float*)(ws + OFF_X2);
    float* y2 = (float*)(ws + OFF_Y2);
    float* part = (float*)(ws + OFF_PART);

    zero_kernel<<<1, 64, 0, stream>>>(out);
    prep_kernel<<<dim3(1024, 2), 256, 0, stream>>>(x, y, xb, yb, x2, y2);
    softmin_fused<<<dim3(NPTS / TILE, 4 * MC, 2), 256, 0, stream>>>(xb, yb, x2, y2, part);
    merge_kernel<<<128, 256, 0, stream>>>(part, out);
}

// Round 8
// 73.644 us; speedup vs baseline: 3.6136x; 3.6136x over previous
//
#include <hip/hip_runtime.h>
#include <math.h>

#define BATCH 4
#define NPTS 4096
#define DF 64
#define ROWB 128               // bytes per point row in bf16
#define TILE 64                // col tile per iter
#define MC 4                   // col splits for occupancy
#define CHUNK (NPTS / MC)      // 1024
#define ITERS (CHUNK / TILE)   // 16
#define INV_T 100.0f
#define MARGIN 0.16f           // skipped weights < exp(-16) ~ 1.1e-7
#define SCALE (1.0f / 16384.0f)

typedef float  f32x4 __attribute__((ext_vector_type(4)));
typedef short  s16x8 __attribute__((ext_vector_type(8)));
typedef unsigned short u16;

// ws layout (6.19 MB, proven in R2/R4)
#define SZ_B   (BATCH * NPTS * DF * 2)   // bf16 array: 2 MB
#define SZ_N   (BATCH * NPTS * 4)        // norm array: 64 KB
#define OFF_XB 0
#define OFF_YB (OFF_XB + SZ_B)
#define OFF_X2 (OFF_YB + SZ_B)
#define OFF_Y2 (OFF_X2 + SZ_N)
#define OFF_PART (OFF_Y2 + SZ_N)         // [dir*4+b][MC][NPTS][4] floats: 2 MB

__device__ __forceinline__ u16 f2bf(float f) {
    unsigned u = __float_as_uint(f);
    unsigned r = (u + 0x7fffu + ((u >> 16) & 1u)) >> 16;   // RNE
    return (u16)r;
}

// async 16B global -> LDS (DMA, no VGPR round-trip)
__device__ __forceinline__ void async16(void* lds, const void* g) {
    __builtin_amdgcn_global_load_lds(
        (const __attribute__((address_space(1))) unsigned int*)g,
        (__attribute__((address_space(3))) unsigned int*)lds, 16, 0, 0);
}

// fp32 -> bf16 (XOR-swizzled row layout: byte ^= (point&7)<<4) + fp32 norms.
// Pre-swizzling in global: linear global_load_lds DMA reproduces the
// bank-conflict-free LDS layout, and register fragment loads can read the
// same offsets directly from global (m173 pattern). Also zeroes out[0].
__global__ __launch_bounds__(256) void prep_kernel(const float* __restrict__ X,
                                                   const float* __restrict__ Y,
                                                   u16* __restrict__ xb, u16* __restrict__ yb,
                                                   float* __restrict__ x2, float* __restrict__ y2,
                                                   float* __restrict__ out) {
    if (blockIdx.x == 0 && blockIdx.y == 0 && threadIdx.x == 0) out[0] = 0.0f;
    const float* src = blockIdx.y ? Y : X;
    u16* dstb   = blockIdx.y ? yb : xb;
    float* dstn = blockIdx.y ? y2 : x2;
    int g = blockIdx.x * 256 + threadIdx.x;
    int p = g >> 4;                       // point 0..16383
    int sub = g & 15;                     // 8B chunk within row
    float4 v = ((const float4*)src)[(size_t)p * 16 + sub];
    float n4 = v.x * v.x + v.y * v.y + v.z * v.z + v.w * v.w;
    #pragma unroll
    for (int m = 1; m < 16; m <<= 1) n4 += __shfl_xor(n4, m, 16);
    ushort4 hh;
    hh.x = f2bf(v.x); hh.y = f2bf(v.y); hh.z = f2bf(v.z); hh.w = f2bf(v.w);
    int byteoff = (sub << 3) ^ ((p & 7) << 4);   // swizzle (XOR bits 4..6)
    *(ushort4*)((char*)dstb + (size_t)p * ROWB + byteoff) = hh;
    if (sub == 0) dstn[p] = n4;
}

// Two-phase partial softmin. Block = 64 rows x 1024 cols of one (b, dir).
// Wave tiling 2x2. Pass 1: exact chunk max of u = xy - y2/2 (-> exact min d).
// Pass 2: per-(st,ct,r) gated weighted sums. A-frags direct from pre-swizzled
// global (no x LDS). launch_bounds min-waves=4: VGPR budget 128, compiler
// lands ~52 <= 64 => HW still fits 8 waves/SIMD (R7's =8 forced spills).
__global__ __launch_bounds__(256, 4) void softmin_fused(const u16* __restrict__ xb,
                                                        const u16* __restrict__ yb,
                                                        const float* __restrict__ x2g,
                                                        const float* __restrict__ y2g,
                                                        float* __restrict__ part) {
    __shared__ u16 ys[2][TILE * DF];     // 2 x 8 KB double buffer
    __shared__ float xchg[4][32][2];

    const int tid = threadIdx.x;
    const int nt  = blockIdx.x;
    const int b   = blockIdx.y & 3;
    const int cs  = blockIdx.y >> 2;
    const int dir = blockIdx.z;

    const u16 *rowsrc, *colsrc; const float *rn, *cn;
    if (dir == 0) { rowsrc = xb; colsrc = yb; rn = x2g; cn = y2g; }
    else          { rowsrc = yb; colsrc = xb; rn = y2g; cn = x2g; }

    const int w    = tid >> 6;
    const int wrow = w >> 1, wcol = w & 1;
    const int h    = (tid >> 4) & 3;     // k-octet / D-row group
    const int c    = tid & 15;           // fragment lane slot

    const size_t bpts = (size_t)b * NPTS;
    const int row0 = nt * TILE;
    const u16* rbase = rowsrc + (bpts + row0) * DF;
    const u16* cbase = colsrc + (bpts + (size_t)cs * CHUNK) * DF;
    const float* cnb = cn + bpts + (size_t)cs * CHUNK;

    // loop-invariant B fragment offsets + col point ids
    int boff[2][2], pty[2];
    #pragma unroll
    for (int ct = 0; ct < 2; ++ct) {
        int p = (wcol * 2 + ct) * 16 + c;
        pty[ct] = p;
        #pragma unroll
        for (int kp = 0; kp < 2; ++kp)
            boff[ct][kp] = p * ROWB + ((h * 16 + kp * 64) ^ ((p & 7) << 4));
    }

    // ---- prologue: DMA first y tile; A-frags + norms direct from global ----
    #pragma unroll
    for (int q = 0; q < 2; ++q) {
        int e = q * 256 + tid;
        async16((char*)ys[0] + e * 16, (const char*)cbase + e * 16);
    }
    float cy[2] = { cnb[pty[0]], cnb[pty[1]] };

    // A fragments (persistent in registers) from pre-swizzled global
    s16x8 afrag[2][2];
    #pragma unroll
    for (int st = 0; st < 2; ++st) {
        int rr = (wrow * 2 + st) * 16 + c;
        #pragma unroll
        for (int kp = 0; kp < 2; ++kp) {
            int o = (h * 16 + kp * 64) ^ ((rr & 7) << 4);
            afrag[st][kp] = *(const s16x8*)((const char*)rbase + rr * ROWB + o);
        }
    }
    float x2v[2][4];
    #pragma unroll
    for (int st = 0; st < 2; ++st)
        #pragma unroll
        for (int r = 0; r < 4; ++r)
            x2v[st][r] = rn[bpts + row0 + (wrow * 2 + st) * 16 + 4 * h + r];

    float mx[2][4];
    #pragma unroll
    for (int st = 0; st < 2; ++st)
        #pragma unroll
        for (int r = 0; r < 4; ++r) mx[st][r] = -INFINITY;

    __syncthreads();   // drains vmcnt(0): ys[0] ready

    // ================= PASS 1: exact chunk max of u = acc - y2/2 =================
    for (int it = 0; it < ITERS; ++it) {
        if (it > 0) __syncthreads();     // waits this iter's DMA (vmcnt 0) + barrier
        float ccy[2] = { cy[0], cy[1] };
        if (it + 1 < ITERS) {            // issue next tile AFTER barrier (overlaps compute)
            const char* nsrc = (const char*)(cbase + (size_t)(it + 1) * TILE * DF);
            char* nbuf = (char*)ys[(it + 1) & 1];
            #pragma unroll
            for (int q = 0; q < 2; ++q) {
                int e = q * 256 + tid;
                async16(nbuf + e * 16, nsrc + e * 16);
            }
            cy[0] = cnb[(it + 1) * TILE + pty[0]];
            cy[1] = cnb[(it + 1) * TILE + pty[1]];
        }
        const char* bptr = (const char*)ys[it & 1];

        s16x8 bf[2][2];
        #pragma unroll
        for (int ct = 0; ct < 2; ++ct)
            #pragma unroll
            for (int kp = 0; kp < 2; ++kp)
                bf[ct][kp] = *(const s16x8*)(bptr + boff[ct][kp]);
        #pragma unroll
        for (int st = 0; st < 2; ++st)
            #pragma unroll
            for (int ct = 0; ct < 2; ++ct) {
                f32x4 a = {0.f, 0.f, 0.f, 0.f};
                a = __builtin_amdgcn_mfma_f32_16x16x32_bf16(afrag[st][0], bf[ct][0], a, 0, 0, 0);
                a = __builtin_amdgcn_mfma_f32_16x16x32_bf16(afrag[st][1], bf[ct][1], a, 0, 0, 0);
                #pragma unroll
                for (int r = 0; r < 4; ++r)
                    mx[st][r] = fmaxf(mx[st][r], fmaf(-0.5f, ccy[ct], a[r]));
            }
    }

    // butterfly max within 16-lane col groups, then share across wcol pair
    #pragma unroll
    for (int st = 0; st < 2; ++st)
        #pragma unroll
        for (int r = 0; r < 4; ++r)
            #pragma unroll
            for (int m = 1; m < 16; m <<= 1)
                mx[st][r] = fmaxf(mx[st][r], __shfl_xor(mx[st][r], m, 16));
    __syncthreads();
    if (c == 0) {
        #pragma unroll
        for (int st = 0; st < 2; ++st)
            #pragma unroll
            for (int r = 0; r < 4; ++r)
                xchg[w][st * 16 + 4 * h + r][0] = mx[st][r];
    }
    __syncthreads();
    #pragma unroll
    for (int st = 0; st < 2; ++st)
        #pragma unroll
        for (int r = 0; r < 4; ++r)
            mx[st][r] = fmaxf(mx[st][r], xchg[w ^ 1][st * 16 + 4 * h + r][0]);

    float mval[2][4], gthr[2][4], ssum[2][4], tsum[2][4];
    #pragma unroll
    for (int st = 0; st < 2; ++st)
        #pragma unroll
        for (int r = 0; r < 4; ++r) {
            float d2m = fmaf(-2.f, mx[st][r], x2v[st][r]);   // exact min d^2
            mval[st][r] = sqrtf(fmaxf(d2m, 0.f));
            gthr[st][r] = mx[st][r] - MARGIN * mval[st][r] - 0.5f * MARGIN * MARGIN;
            ssum[st][r] = 0.f; tsum[st][r] = 0.f;
        }

    // re-prologue for pass 2 (safe: pass-1 reads fully done)
    #pragma unroll
    for (int q = 0; q < 2; ++q) {
        int e = q * 256 + tid;
        async16((char*)ys[0] + e * 16, (const char*)cbase + e * 16);
    }
    cy[0] = cnb[pty[0]]; cy[1] = cnb[pty[1]];

    // ================= PASS 2: gated weighted sums =================
    for (int it = 0; it < ITERS; ++it) {
        __syncthreads();                 // waits this iter's DMA + barrier
        float ccy[2] = { cy[0], cy[1] };
        if (it + 1 < ITERS) {
            const char* nsrc = (const char*)(cbase + (size_t)(it + 1) * TILE * DF);
            char* nbuf = (char*)ys[(it + 1) & 1];
            #pragma unroll
            for (int q = 0; q < 2; ++q) {
                int e = q * 256 + tid;
                async16(nbuf + e * 16, nsrc + e * 16);
            }
            cy[0] = cnb[(it + 1) * TILE + pty[0]];
            cy[1] = cnb[(it + 1) * TILE + pty[1]];
        }
        const char* bptr = (const char*)ys[it & 1];

        s16x8 bf[2][2];
        #pragma unroll
        for (int ct = 0; ct < 2; ++ct)
            #pragma unroll
            for (int kp = 0; kp < 2; ++kp)
                bf[ct][kp] = *(const s16x8*)(bptr + boff[ct][kp]);
        #pragma unroll
        for (int st = 0; st < 2; ++st)
            #pragma unroll
            for (int ct = 0; ct < 2; ++ct) {
                f32x4 a = {0.f, 0.f, 0.f, 0.f};
                a = __builtin_amdgcn_mfma_f32_16x16x32_bf16(afrag[st][0], bf[ct][0], a, 0, 0, 0);
                a = __builtin_amdgcn_mfma_f32_16x16x32_bf16(afrag[st][1], bf[ct][1], a, 0, 0, 0);
                #pragma unroll
                for (int r = 0; r < 4; ++r) {
                    float u = fmaf(-0.5f, ccy[ct], a[r]);
                    if (__any(u > gthr[st][r])) {    // 4-row x 16-col slice, ~9% fire
                        float d2 = fmaf(-2.f, u, x2v[st][r]);
                        float d = sqrtf(fmaxf(d2, 0.f));
                        float e = __expf(INV_T * (mval[st][r] - d));  // ->0 if far
                        ssum[st][r] += e;
                        tsum[st][r] = fmaf(e, d, tsum[st][r]);
                    }
                }
            }
    }

    // butterfly sums within 16-lane col groups
    #pragma unroll
    for (int st = 0; st < 2; ++st)
        #pragma unroll
        for (int r = 0; r < 4; ++r)
            #pragma unroll
            for (int m = 1; m < 16; m <<= 1) {
                ssum[st][r] += __shfl_xor(ssum[st][r], m, 16);
                tsum[st][r] += __shfl_xor(tsum[st][r], m, 16);
            }

    // cross-wcol add and partial-state write
    __syncthreads();
    if (c == 0) {
        #pragma unroll
        for (int st = 0; st < 2; ++st)
            #pragma unroll
            for (int r = 0; r < 4; ++r) {
                xchg[w][st * 16 + 4 * h + r][0] = ssum[st][r];
                xchg[w][st * 16 + 4 * h + r][1] = tsum[st][r];
            }
    }
    __syncthreads();
    if (wcol == 0 && c == 0) {
        int dirb = dir * 4 + b;
        #pragma unroll
        for (int st = 0; st < 2; ++st)
            #pragma unroll
            for (int r = 0; r < 4; ++r) {
                int row32 = st * 16 + 4 * h + r;
                float S = ssum[st][r] + xchg[w + 1][row32][0];
                float T = tsum[st][r] + xchg[w + 1][row32][1];
                int row = row0 + wrow * 32 + row32;
                float* pp = part + (((size_t)(dirb * MC + cs)) * NPTS + row) * 4;
                pp[0] = mval[st][r]; pp[1] = S; pp[2] = T;
            }
    }
}

// Merge MC partial states per row, cube, reduce, atomicAdd into out[0].
__global__ __launch_bounds__(256) void merge_kernel(const float* __restrict__ part,
                                                    float* __restrict__ out) {
    __shared__ float red[4];
    int g = blockIdx.x * 256 + threadIdx.x;   // (dir*4+b)*4096 + row
    int dirb = g >> 12;
    int row  = g & 4095;
    const float* p0 = part + (((size_t)dirb * MC) * NPTS + row) * 4;
    float mnv[MC], sv[MC], tv[MC];
    float nm = INFINITY;
    #pragma unroll
    for (int k = 0; k < MC; ++k) {
        const float* p = p0 + (size_t)k * NPTS * 4;
        mnv[k] = p[0]; sv[k] = p[1]; tv[k] = p[2];
        nm = fminf(nm, mnv[k]);
    }
    float S = 0.f, T = 0.f;
    #pragma unroll
    for (int k = 0; k < MC; ++k) {
        float cw = __expf(INV_T * (nm - mnv[k]));
        S += sv[k] * cw;
        T += tv[k] * cw;
    }
    float sm = T / S;
    float v = sm * sm * sm * SCALE;
    #pragma unroll
    for (int m = 1; m < 64; m <<= 1) v += __shfl_xor(v, m, 64);
    if ((threadIdx.x & 63) == 0) red[threadIdx.x >> 6] = v;
    __syncthreads();
    if (threadIdx.x == 0) atomicAdd(out, red[0] + red[1] + red[2] + red[3]);
}

extern "C" void kernel_launch(void* const* d_in, const int* in_sizes, int n_in,
                              void* d_out, int out_size, void* d_ws, size_t ws_size,
                              hipStream_t stream) {
    const float* x = (const float*)d_in[0];
    const float* y = (const float*)d_in[1];
    float* out = (float*)d_out;
    char* ws = (char*)d_ws;

    u16* xb = (u16*)(ws + OFF_XB);
    u16* yb = (u16*)(ws + OFF_YB);
    float* x2 = (float*)(ws + OFF_X2);
    float* y2 = (float*)(ws + OFF_Y2);
    float* part = (float*)(ws + OFF_PART);

    prep_kernel<<<dim3(1024, 2), 256, 0, stream>>>(x, y, xb, yb, x2, y2, out);
    softmin_fused<<<dim3(NPTS / TILE, 4 * MC, 2), 256, 0, stream>>>(xb, yb, x2, y2, part);
    merge_kernel<<<128, 256, 0, stream>>>(part, out);
}